// Round 4
// baseline (166.449 us; speedup 1.0000x reference)
//
#include <hip/hip_runtime.h>
#include <hip/hip_bf16.h>

// Problem (fp32 in/out): x[1][16][10][32][64][64], W[4][16][3][3][3][3], b[4]
// out[1][4][10][32][64][64] = softmax_over_channel(conv4d(x,W,pad=1)+b)
//
// R11: transpose_x rewritten LDS-free. Each thread: one (row, x-pair, ci-half),
// 8x float2 reads (wave-instr = 2x256B contiguous), cvt_pk pack, 2x dwordx4
// store (wave pair covers row contiguously). No LDS (old version had 8-way
// write bank conflicts), no barrier, ~40 VGPR -> full latency hiding.
// conv: R10 z-pair structure retained (4 blk/CU).
#define CIN  16
#define COUT 4
#define TT   10
#define ZZ   32
#define YY   64
#define XX   64

constexpr int SX_CI = TT * ZZ * YY * XX;  // 1310720
constexpr int SX_T  = ZZ * YY * XX;       // 131072
constexpr int SX_Z  = YY * XX;            // 4096
constexpr int WCO   = CIN * 81;           // 1296

constexpr int XT_TB = ZZ * YY * XX * CIN * 2;  // 4194304
constexpr int XT_ZB = YY * XX * CIN * 2;       // 131072
constexpr int XT_YB = XX * CIN * 2;            // 2048 (one row)
constexpr size_t XT_BYTES = (size_t)TT * XT_TB;    // 41,943,040
constexpr size_t BTAB     = XT_BYTES;              // 9 planes x 2 frags x 1KB
constexpr size_t ZOFF     = BTAB + 9 * 2048;       // 2048B zero row
constexpr size_t WS_NEED  = ZOFF + 2048;

typedef short  short8 __attribute__((ext_vector_type(8)));
typedef float  f32x4  __attribute__((ext_vector_type(4)));

__device__ __forceinline__ unsigned short f2bf(float f) {
    union { __hip_bfloat16 h; unsigned short u; } c;
    c.h = __float2bfloat16(f);
    return c.u;
}
__device__ __forceinline__ unsigned int pk(float a, float b) {
    return (unsigned int)f2bf(a) | ((unsigned int)f2bf(b) << 16);
}

// ---- transpose v5 (R11): LDS-free direct pack+store ----
// Row r=(t,z,y): 2048B = 64 x * (16 ci * 2B). Thread (r, xp, h):
// reads x[h*8+j][r_base + 2*xp + {0,1}] as float2 (j=0..7), packs 8 bf16-pair
// words, stores 16B chunks for x=2xp and x=2xp+1 at [x*32 + h*16].
// Wave = one row: reads 2x256B/instr, stores interleave to full coverage.
__global__ __launch_bounds__(256) void transpose_x(const float* __restrict__ x,
                                                   char* __restrict__ ws) {
    const int tid = threadIdx.x;
    const int wid = tid >> 6;            // row within block (0..3)
    const int i   = tid & 63;
    const int xp  = i >> 1;              // x-pair 0..31
    const int h   = i & 1;               // ci half (0: ci 0-7, 1: ci 8-15)
    const int r   = blockIdx.x * 4 + wid;    // global row 0..20479
    const int t   = r >> 11;             // 2048 rows per t
    const int rem = r & 2047;
    const int z   = rem >> 6;
    const int y   = rem & 63;
    const size_t base = (size_t)t * SX_T + (size_t)z * SX_Z +
                        (size_t)y * XX + 2 * xp;
    float2 v[8];
#pragma unroll
    for (int j = 0; j < 8; ++j)
        v[j] = *(const float2*)(x + (size_t)(h * 8 + j) * SX_CI + base);
    unsigned int w0[4], w1[4];
#pragma unroll
    for (int k = 0; k < 4; ++k) {
        w0[k] = pk(v[2 * k].x, v[2 * k + 1].x);   // word 4h+k of x=2xp
        w1[k] = pk(v[2 * k].y, v[2 * k + 1].y);   // word 4h+k of x=2xp+1
    }
    char* rowp = ws + (size_t)r * 2048 + xp * 64 + h * 16;
    *(uint4*)(rowp)      = make_uint4(w0[0], w0[1], w0[2], w0[3]);
    *(uint4*)(rowp + 32) = make_uint4(w1[0], w1[1], w1[2], w1[3]);
}

// ---- prep: B-fragment tables + zero row (verified R7) ----
__global__ void prep_B(const float* __restrict__ W, char* __restrict__ ws) {
    const int g = blockIdx.x * 256 + threadIdx.x;
    if (g < 1152) {
        const int p = g >> 7, rem = g & 127, frag = rem >> 6, L = rem & 63;
        const int q = L >> 4, n = L & 15, co = n & 3, dx = n >> 2;
        const int dt = p / 3, dz = p % 3;
        unsigned int d[4];
#pragma unroll
        for (int j = 0; j < 4; ++j) {
            float v0 = 0.f, v1 = 0.f;
            if (dx < 3) {
                if (frag == 0) {
                    const int dy = q >> 1;
                    const int ci0 = (q & 1) * 8 + 2 * j;
                    v0 = W[(co * CIN + ci0) * 81 + dt * 27 + dz * 9 + dy * 3 + dx];
                    v1 = W[(co * CIN + ci0 + 1) * 81 + dt * 27 + dz * 9 + dy * 3 + dx];
                } else if (q < 2) {
                    const int ci0 = q * 8 + 2 * j;
                    v0 = W[(co * CIN + ci0) * 81 + dt * 27 + dz * 9 + 6 + dx];
                    v1 = W[(co * CIN + ci0 + 1) * 81 + dt * 27 + dz * 9 + 6 + dx];
                }
            }
            d[j] = pk(v0, v1);
        }
        *(uint4*)(ws + BTAB + (size_t)p * 2048 + frag * 1024 + (size_t)L * 16) =
            make_uint4(d[0], d[1], d[2], d[3]);
    } else if (g < 1280) {
        *(uint4*)(ws + ZOFF + (size_t)(g - 1152) * 16) = make_uint4(0, 0, 0, 0);
    }
}

#define GL16(SRC, DST) __builtin_amdgcn_global_load_lds( \
    (const __attribute__((address_space(1))) unsigned int*)(SRC), \
    (__attribute__((address_space(3))) unsigned int*)(DST), 16, 0, 0)

#define LROW 21
__global__ __launch_bounds__(256, 4) void conv_mfma(
        const char* __restrict__ ws,
        const float* __restrict__ bias,
        float* __restrict__ out) {
    __shared__ char smem[2 * 10 * 2048];   // 40,960 B double buffer -> 4 blk/CU
    const int lane = threadIdx.x;
    const int wid  = __builtin_amdgcn_readfirstlane(threadIdx.y);
    // XCD swizzle: z-slab (4 z) per XCD, t-major order
    const int bid = blockIdx.x;
    const int xcd = bid & 7, lid = bid >> 3;   // lid 0..159
    const int z0 = 4 * xcd + 2 * (lid & 1);    // even z; block does z0, z0+1
    const int yq = (lid >> 1) & 7;
    const int t0 = lid >> 4;
    const int y0 = yq * 8;
    const int m = lane & 15, q = lane >> 4, h = q & 1, dyA = q >> 1;
    const int e2 = 2 * m + h;
    const int wid2 = wid * 2;

    f32x4 acc[2][2][4];   // [z][r][xt]
#pragma unroll
    for (int z = 0; z < 2; ++z)
#pragma unroll
        for (int r = 0; r < 2; ++r)
#pragma unroll
            for (int xt = 0; xt < 4; ++xt) acc[z][r][xt] = (f32x4){0.f, 0.f, 0.f, 0.f};

// Stage plane P (dt=P>>2, zin=z0-1+(P&3)) into buffer BUF: 10 rows x 2KB.
// 20 half-row loads over 4 waves (5/wave). OOB rows/planes -> zero row.
#define STAGE(P, BUF) { \
    constexpr int dtS = (P) >> 2, jS = (P) & 3; \
    const int t_in = t0 + dtS - 1, z_in = z0 + jS - 1; \
    const bool pv = ((unsigned)t_in < TT) && ((unsigned)z_in < ZZ); \
    const int pbase = pv ? (t_in * XT_TB + z_in * XT_ZB) : 0; \
    _Pragma("unroll") \
    for (int k = 0; k < 5; ++k) { \
        const int idx = wid + 4 * k; \
        const int rw = idx >> 1; \
        const int hf = (idx & 1) * 1024; \
        const int y_in = y0 - 1 + rw; \
        const bool rv = pv && ((unsigned)y_in < YY); \
        const char* srcS = ws + (rv ? (size_t)(pbase + y_in * XT_YB) : ZOFF) \
                              + hf + lane * 16; \
        GL16(srcS, smem + (BUF) * 20480 + rw * 2048 + hf + lane * 16); \
    } }

// Compute plane P from buffer BUF. Plane j contributes to z0 (dz=j, j<=2) and
// z1 (dz=j-1, j>=1) -- SAME A-rows (Rw0..3), different B-frags. Static gating
// (P literal) folds the branches.
#define COMPUTE(P, BUF) { \
    constexpr int dtC = (P) >> 2, jC = (P) & 3; \
    constexpr int paC = dtC * 3 + (jC <= 2 ? jC : 0); \
    constexpr int pbC = dtC * 3 + (jC >= 1 ? jC - 1 : 0); \
    const char* bbC = smem + (BUF) * 20480; \
    const short8 BfAa = *(const short8*)(ws + BTAB + paC * 2048 + lane * 16); \
    const short8 BfBa = *(const short8*)(ws + BTAB + paC * 2048 + 1024 + lane * 16); \
    const short8 BfAb = *(const short8*)(ws + BTAB + pbC * 2048 + lane * 16); \
    const short8 BfBb = *(const short8*)(ws + BTAB + pbC * 2048 + 1024 + lane * 16); \
    _Pragma("unroll") \
    for (int xt = 0; xt < 4; ++xt) { \
        const int sw = (32 * xt + e2) * 16; \
        const char* colp = bbC + wid2 * 2048 + sw; \
        const short8 Rw0 = *(const short8*)(colp + 0 * 2048); \
        const short8 Rw1 = *(const short8*)(colp + 1 * 2048); \
        const short8 Rw2 = *(const short8*)(colp + 2 * 2048); \
        const short8 Rw3 = *(const short8*)(colp + 3 * 2048); \
        const short8 fa0 = dyA ? Rw1 : Rw0; \
        const short8 fa1 = dyA ? Rw2 : Rw1; \
        if (jC <= 2) { \
            acc[0][0][xt] = __builtin_amdgcn_mfma_f32_16x16x32_bf16(fa0, BfAa, acc[0][0][xt], 0, 0, 0); \
            acc[0][0][xt] = __builtin_amdgcn_mfma_f32_16x16x32_bf16(Rw2, BfBa, acc[0][0][xt], 0, 0, 0); \
            acc[0][1][xt] = __builtin_amdgcn_mfma_f32_16x16x32_bf16(fa1, BfAa, acc[0][1][xt], 0, 0, 0); \
            acc[0][1][xt] = __builtin_amdgcn_mfma_f32_16x16x32_bf16(Rw3, BfBa, acc[0][1][xt], 0, 0, 0); \
        } \
        if (jC >= 1) { \
            acc[1][0][xt] = __builtin_amdgcn_mfma_f32_16x16x32_bf16(fa0, BfAb, acc[1][0][xt], 0, 0, 0); \
            acc[1][0][xt] = __builtin_amdgcn_mfma_f32_16x16x32_bf16(Rw2, BfBb, acc[1][0][xt], 0, 0, 0); \
            acc[1][1][xt] = __builtin_amdgcn_mfma_f32_16x16x32_bf16(fa1, BfAb, acc[1][1][xt], 0, 0, 0); \
            acc[1][1][xt] = __builtin_amdgcn_mfma_f32_16x16x32_bf16(Rw3, BfBb, acc[1][1][xt], 0, 0, 0); \
        } \
    } }

    // Pipeline: barrier AFTER compute -> stage(P+1) flies under compute(P).
    STAGE(0, 0)  __syncthreads();
    STAGE(1, 1)  COMPUTE(0, 0)  __syncthreads();
    STAGE(2, 0)  COMPUTE(1, 1)  __syncthreads();
    STAGE(3, 1)  COMPUTE(2, 0)  __syncthreads();
    STAGE(4, 0)  COMPUTE(3, 1)  __syncthreads();
    STAGE(5, 1)  COMPUTE(4, 0)  __syncthreads();
    STAGE(6, 0)  COMPUTE(5, 1)  __syncthreads();
    STAGE(7, 1)  COMPUTE(6, 0)  __syncthreads();
    STAGE(8, 0)  COMPUTE(7, 1)  __syncthreads();
    STAGE(9, 1)  COMPUTE(8, 0)  __syncthreads();
    STAGE(10, 0) COMPUTE(9, 1)  __syncthreads();
    STAGE(11, 1) COMPUTE(10, 0) __syncthreads();
    COMPUTE(11, 1) __syncthreads();
#undef STAGE
#undef COMPUTE

    const float bi0 = bias[0], bi1 = bias[1], bi2 = bias[2], bi3 = bias[3];
    float* swave = (float*)smem + wid * (66 * LROW);   // aliases dead staging
    if (lane < LROW) {
        swave[lane] = 0.f;
        swave[65 * LROW + lane] = 0.f;
    }
    const int colw = lane & 15;
    const int rowq = (lane >> 4) * 4 + 1;
#pragma unroll
    for (int z = 0; z < 2; ++z) {
#pragma unroll
        for (int r = 0; r < 2; ++r) {
#pragma unroll
            for (int xt = 0; xt < 4; ++xt)
#pragma unroll
                for (int reg = 0; reg < 4; ++reg)
                    swave[(xt * 16 + rowq + reg) * LROW + colw] = acc[z][r][xt][reg];
            float lg0 = bi0, lg1 = bi1, lg2 = bi2, lg3 = bi3;
#pragma unroll
            for (int dx = 0; dx < 3; ++dx) {
                const float* sp = swave + (lane + dx) * LROW + dx * 4;
                lg0 += sp[0]; lg1 += sp[1]; lg2 += sp[2]; lg3 += sp[3];
            }
            const float mx = fmaxf(fmaxf(lg0, lg1), fmaxf(lg2, lg3));
            const float e0 = __expf(lg0 - mx);
            const float e1 = __expf(lg1 - mx);
            const float e2v = __expf(lg2 - mx);
            const float e3 = __expf(lg3 - mx);
            const float inv = 1.f / (e0 + e1 + e2v + e3);
            const int y = y0 + wid2 + r;
            float* op = out + (size_t)t0 * SX_T + (size_t)(z0 + z) * SX_Z +
                        (size_t)y * XX + lane;
            op[0 * (size_t)SX_CI] = e0 * inv;
            op[1 * (size_t)SX_CI] = e1 * inv;
            op[2 * (size_t)SX_CI] = e2v * inv;
            op[3 * (size_t)SX_CI] = e3 * inv;
        }
    }
}

// ================= fallback (R3 vector kernel) if ws too small =================
__global__ __launch_bounds__(256, 4) void conv4d_softmax_vec(
        const float* __restrict__ x, const float* __restrict__ W,
        const float* __restrict__ b, float* __restrict__ out) {
    const int lane = threadIdx.x;
    const int xg = lane & 15, yl = lane >> 4;
    const int y = blockIdx.x * 16 + threadIdx.y * 4 + yl;
    const int z0 = blockIdx.y, t0 = blockIdx.z, x0 = xg * 4;
    float acc[COUT][4];
#pragma unroll
    for (int c = 0; c < COUT; ++c)
#pragma unroll
        for (int xi = 0; xi < 4; ++xi) acc[c][xi] = 0.f;
    for (int ci = 0; ci < CIN; ++ci) {
        const float* xc = x + (size_t)ci * SX_CI;
        const float* wc = W + ci * 81;
#pragma unroll
        for (int dt = 0; dt < 3; ++dt) {
            const int t_in = t0 + dt - 1;
            const int t_c = min(max(t_in, 0), TT - 1);
            const bool tv = (unsigned)t_in < TT;
#pragma unroll
            for (int dz = 0; dz < 3; ++dz) {
                const int z_in = z0 + dz - 1;
                const int z_c = min(max(z_in, 0), ZZ - 1);
                const bool tzvv = tv && ((unsigned)z_in < ZZ);
                const float* plane = xc + (size_t)t_c * SX_T + (size_t)z_c * SX_Z;
                const float* wb = wc + (dt * 3 + dz) * 9;
#pragma unroll
                for (int e = 0; e < 3; ++e) {
                    const int y_in = y + e - 1;
                    const int y_c = min(max(y_in, 0), YY - 1);
                    const bool v = tzvv && ((unsigned)y_in < YY);
                    float4 f = *(const float4*)(plane + y_c * XX + x0);
                    f.x = v ? f.x : 0.f; f.y = v ? f.y : 0.f;
                    f.z = v ? f.z : 0.f; f.w = v ? f.w : 0.f;
                    float hl = __shfl(f.w, (lane - 1) & 63, 64);
                    hl = (xg == 0) ? 0.f : hl;
                    float hr = __shfl(f.x, (lane + 1) & 63, 64);
                    hr = (xg == 15) ? 0.f : hr;
                    const float win[6] = {hl, f.x, f.y, f.z, f.w, hr};
#pragma unroll
                    for (int co = 0; co < COUT; ++co) {
                        const float* wp = wb + co * WCO + e * 3;
                        const float w0 = wp[0], w1 = wp[1], w2 = wp[2];
#pragma unroll
                        for (int xi = 0; xi < 4; ++xi) {
                            float a = acc[co][xi];
                            a = fmaf(win[xi], w0, a);
                            a = fmaf(win[xi + 1], w1, a);
                            a = fmaf(win[xi + 2], w2, a);
                            acc[co][xi] = a;
                        }
                    }
                }
            }
        }
    }
    const float b0 = b[0], b1 = b[1], b2 = b[2], b3 = b[3];
    float4 rr[COUT];
#pragma unroll
    for (int xi = 0; xi < 4; ++xi) {
        const float a0 = acc[0][xi] + b0, a1 = acc[1][xi] + b1;
        const float a2 = acc[2][xi] + b2, a3 = acc[3][xi] + b3;
        const float mm = fmaxf(fmaxf(a0, a1), fmaxf(a2, a3));
        const float e0 = __expf(a0 - mm), e1 = __expf(a1 - mm);
        const float e2 = __expf(a2 - mm), e3 = __expf(a3 - mm);
        const float inv = 1.f / (e0 + e1 + e2 + e3);
        ((float*)&rr[0])[xi] = e0 * inv; ((float*)&rr[1])[xi] = e1 * inv;
        ((float*)&rr[2])[xi] = e2 * inv; ((float*)&rr[3])[xi] = e3 * inv;
    }
    float* op = out + (size_t)t0 * SX_T + (size_t)z0 * SX_Z + (size_t)y * XX + x0;
#pragma unroll
    for (int co = 0; co < COUT; ++co)
        *(float4*)(op + (size_t)co * SX_CI) = rr[co];
}

extern "C" void kernel_launch(void* const* d_in, const int* in_sizes, int n_in,
                              void* d_out, int out_size, void* d_ws, size_t ws_size,
                              hipStream_t stream) {
    const float* x = (const float*)d_in[0];
    const float* W = (const float*)d_in[1];
    const float* b = (const float*)d_in[2];
    float* out = (float*)d_out;

    if (ws_size >= WS_NEED) {
        char* ws = (char*)d_ws;
        transpose_x<<<dim3(5120), dim3(256), 0, stream>>>(x, ws);
        prep_B<<<dim3(5), dim3(256), 0, stream>>>(W, ws);
        conv_mfma<<<dim3(1280), dim3(64, 4), 0, stream>>>(ws, b, out);
    } else {
        conv4d_softmax_vec<<<dim3(4, ZZ, TT), dim3(64, 4), 0, stream>>>(x, W, b, out);
    }
}